// Round 1
// baseline (188.338 us; speedup 1.0000x reference)
//
#include <hip/hip_runtime.h>

// Problem constants (from reference): B=16, C=1, H=1024, W=1024, fp32.
#define HH 1024
#define WW 1024
#define RPB 16           // rows per block (rolling window marches down 16 rows)
#define NT 256

__device__ __forceinline__ float fmax3(float a, float b, float c) {
    return fmaxf(a, fmaxf(b, c));
}

__device__ __forceinline__ float loss_elem(float x, float t, float dil) {
    // target/dilated are exactly binary {0,1}: weight = 1 + 4*dil + 15*t
    float w = fmaf(15.0f, t, fmaf(4.0f, dil, 1.0f));
    // BCE with logits: max(x,0) - x*t + log1p(exp(-|x|))
    float a  = fabsf(x);
    float sp = __logf(1.0f + __expf(-a));
    return w * (fmaxf(x, 0.0f) - x * t + sp);
}

// R10: rolling-window streaming version.
//  - Old structure: 18-load burst per wave, one vmcnt drain, wave dies.
//    2048 blocks at ~4 resident blocks/CU => TWO dispatch generations
//    (Occupancy 33%) and a 147MB one-shot queue draining at 3.4 TB/s.
//  - New: 1024 blocks x 16-row slabs, whole grid co-resident in ONE
//    generation. Per row: prefetch T[r+3]/X[r+2], compute row r from a
//    5-deep register window => sustained paced issue (copy-ubench shape),
//    effective prefetch depth 2 rows (~4KB/wave in flight steady-state).
//  - Halo re-read overhead halves: 18 target rows per 16 output rows
//    (12.5%) vs 10 per 8 (25%): 147MB -> 139MB.
//  - XCD swizzle: each XCD owns rows [128x, 128x+128) of every image;
//    vertically adjacent slabs (sharing halo rows) land on the same XCD
//    consecutively -> halo rows hit local L2.
template <bool PER_WAVE>
__global__ __launch_bounds__(NT, 4) void dilatedweightBCE_main(
        const float* __restrict__ pred,
        const float* __restrict__ target,
        float* __restrict__ partial) {
    __shared__ float swave[NT / 64];

    const int t    = threadIdx.x;
    const int lane = t & 63;
    const int wv   = t >> 6;
    const int c    = t * 4;                  // column strip (NT*4 == WW)

    // --- XCD-contiguous swizzle: l -> (img, h0) ---
    const int l    = blockIdx.x;             // [0, 1024)
    const int xcd  = l & 7;
    const int j    = l >> 3;                 // [0, 128)
    const int img  = j >> 3;                 // [0, 16)
    const int slab = j & 7;                  // [0, 8)
    const int h0   = xcd * (8 * RPB) + slab * RPB;   // XCD x owns rows [128x,128x+128)

    const float* timg = target + (size_t)img * HH * WW;
    const float* pimg = pred   + (size_t)img * HH * WW;
    const float* tp   = timg + (size_t)h0 * WW + c;   // target row pointer (this strip)
    const float* pp   = pimg + (size_t)h0 * WW + c;   // pred row pointer

    const bool top = (h0 > 0);
    const bool bot = (h0 + RPB < HH);
    const float4 zero = make_float4(0.0f, 0.0f, 0.0f, 0.0f);

    // halo column (c-1 for lane0, c+4 for lane63) — 2 lanes/wave, L1/L2 hits
    const bool hval = (lane == 0) ? (c > 0) : ((lane == 63) ? (c + 4 < WW) : false);
    const float* thp = timg + (size_t)h0 * WW + ((lane == 0) ? (c - 1) : (c + 4));

    // Rolling register windows. Indices are (row+k)%5 / %3 with r a
    // compile-time constant after full unroll => pure SSA registers
    // (rule: no runtime-indexed arrays -> scratch).
    float4 T[5];                // target rows r-1 .. r+3   slot(row) = (row+1)%5
    float4 X[3];                // pred   rows r   .. r+2   slot(row) = row%3
    float  hv[5];               // halo column, same slotting as T
    #pragma unroll
    for (int i = 0; i < 5; ++i) hv[i] = 0.0f;

    // ---- prologue: rows -1..2 of target, 0..1 of pred ----
    T[0] = top ? *(const float4*)(tp - WW) : zero;
    T[1] = *(const float4*)(tp);
    T[2] = *(const float4*)(tp + WW);
    T[3] = *(const float4*)(tp + 2 * WW);
    X[0] = *(const float4*)(pp);
    X[1] = *(const float4*)(pp + WW);
    if (hval) {
        if (top) hv[0] = *(thp - WW);
        hv[1] = thp[0];
        hv[2] = thp[WW];
        hv[3] = thp[2 * WW];
    }

    float s = 0.0f;
    #pragma unroll
    for (int r = 0; r < RPB; ++r) {
        // ---- prefetch: target row r+3 (+halo), pred row r+2 ----
        // Written slots (r+4)%5 / (r+2)%3 are disjoint from the slots
        // read below ((r..r+2)%5, r%3).
        if (r + 3 < RPB) {
            T[(r + 4) % 5] = *(const float4*)(tp + (size_t)(r + 3) * WW);
            float hnew = 0.0f;
            if (hval) hnew = thp[(size_t)(r + 3) * WW];
            hv[(r + 4) % 5] = hnew;
        } else if (r + 3 == RPB) {          // bottom halo row (or zero at image edge)
            T[(r + 4) % 5] = bot ? *(const float4*)(tp + (size_t)RPB * WW) : zero;
            float hnew = 0.0f;
            if (hval && bot) hnew = thp[(size_t)RPB * WW];
            hv[(r + 4) % 5] = hnew;
        }
        if (r + 2 < RPB)
            X[(r + 2) % 3] = *(const float4*)(pp + (size_t)(r + 2) * WW);

        // ---- dilation + loss for row r ----
        float4 a = T[r % 5], m = T[(r + 1) % 5], d = T[(r + 2) % 5];
        float4 vm = make_float4(fmax3(a.x, m.x, d.x), fmax3(a.y, m.y, d.y),
                                fmax3(a.z, m.z, d.z), fmax3(a.w, m.w, d.w));

        float hmax = fmax3(hv[r % 5], hv[(r + 1) % 5], hv[(r + 2) % 5]);
        float lft = __shfl_up(vm.w, 1);
        float rgt = __shfl_down(vm.x, 1);
        if (lane == 0)  lft = hmax;
        if (lane == 63) rgt = hmax;

        float d0 = fmax3(lft,  vm.x, vm.y);
        float d1 = fmax3(vm.x, vm.y, vm.z);
        float d2 = fmax3(vm.y, vm.z, vm.w);
        float d3 = fmax3(vm.z, vm.w, rgt);

        float4 x = X[r % 3];
        s += loss_elem(x.x, m.x, d0);
        s += loss_elem(x.y, m.y, d1);
        s += loss_elem(x.z, m.z, d2);
        s += loss_elem(x.w, m.w, d3);
    }

    // ---- wave reduction ----
    #pragma unroll
    for (int off = 32; off > 0; off >>= 1)
        s += __shfl_down(s, off);

    if (PER_WAVE) {
        if (lane == 0)
            partial[(size_t)l * (NT / 64) + wv] = s;   // no barrier, no LDS
    } else {
        if (lane == 0) swave[wv] = s;
        __syncthreads();
        if (t == 0) {
            float tot = 0.0f;
            #pragma unroll
            for (int i = 0; i < NT / 64; ++i) tot += swave[i];
            partial[l] = tot;
        }
    }
}

__global__ __launch_bounds__(1024) void dilatedweightBCE_reduce(
        const float* __restrict__ partial,
        float* __restrict__ out,
        int npart4,            // number of float4 chunks
        float inv_n) {
    __shared__ float swave[16];
    const int t = threadIdx.x;

    float s = 0.0f;
    const float4* p4 = (const float4*)partial;
    for (int i = t; i < npart4; i += 1024) {
        float4 v = p4[i];
        s += v.x + v.y + v.z + v.w;
    }

    #pragma unroll
    for (int off = 32; off > 0; off >>= 1)
        s += __shfl_down(s, off);

    const int lane = t & 63;
    if (lane == 0) swave[t >> 6] = s;
    __syncthreads();
    if (t == 0) {
        float tot = 0.0f;
        #pragma unroll
        for (int i = 0; i < 16; ++i) tot += swave[i];
        out[0] = tot * inv_n;
    }
}

extern "C" void kernel_launch(void* const* d_in, const int* in_sizes, int n_in,
                              void* d_out, int out_size, void* d_ws, size_t ws_size,
                              hipStream_t stream) {
    const float* pred   = (const float*)d_in[0];
    const float* target = (const float*)d_in[1];
    float* out     = (float*)d_out;
    float* partial = (float*)d_ws;

    const int n  = in_sizes[0];              // B*C*H*W
    const int Bn = n / (HH * WW);            // batch (16)
    const int nblocks = (HH / RPB) * Bn;     // 1024

    const size_t need = (size_t)nblocks * (NT / 64) * sizeof(float);  // 16 KB
    if (ws_size >= need) {
        dilatedweightBCE_main<true><<<nblocks, NT, 0, stream>>>(pred, target, partial);
        dilatedweightBCE_reduce<<<1, 1024, 0, stream>>>(partial, out,
                                                        nblocks * (NT / 64) / 4,
                                                        1.0f / (float)n);
    } else {
        dilatedweightBCE_main<false><<<nblocks, NT, 0, stream>>>(pred, target, partial);
        dilatedweightBCE_reduce<<<1, 1024, 0, stream>>>(partial, out,
                                                        nblocks / 4,
                                                        1.0f / (float)n);
    }
}

// Round 2
// 185.382 us; speedup vs baseline: 1.0159x; 1.0159x over previous
//
#include <hip/hip_runtime.h>

// Problem constants (from reference): B=16, C=1, H=1024, W=1024, fp32.
#define HH 1024
#define WW 1024
#define RPB 16           // rows per block (rolling window marches down 16 rows)
#define NT 256

__device__ __forceinline__ float fmax3(float a, float b, float c) {
    return fmaxf(a, fmaxf(b, c));
}

__device__ __forceinline__ float loss_elem(float x, float t, float dil) {
    // target/dilated are exactly binary {0,1}: weight = 1 + 4*dil + 15*t
    float w = fmaf(15.0f, t, fmaf(4.0f, dil, 1.0f));
    // BCE with logits: max(x,0) - x*t + log1p(exp(-|x|))
    float a  = fabsf(x);
    float sp = __logf(1.0f + __expf(-a));
    return w * (fmaxf(x, 0.0f) - x * t + sp);
}

// R11: rolling-window streaming, NAMED-REGISTER edition.
//   R10 post-mortem: T[(r+4)%5] arrays went to scratch (SROA runs before
//   unroll) -> 88MB scratch writes, 97us. Rule #20 fix: hand-unrolled
//   steps with named vars tA..tE / xA..xC / hA..hE; rotation is explicit
//   register copies that copy-propagate to nothing.
//   Structure vs R9 burst (42.9us): 1024 blocks x 16-row slabs
//   (one co-resident generation, 4 blocks/CU), halo re-read overhead
//   12.5% vs 25% (147MB -> 139MB), paced sequential issue with 3-row
//   lookahead instead of 18-load burst + single vmcnt drain.
//   XCD swizzle: XCD x owns rows [128x,128x+128) of each image ->
//   vertically adjacent slabs (sharing halo rows) hit the local L2.
template <bool PER_WAVE>
__global__ __launch_bounds__(NT, 4) void dilatedweightBCE_main(
        const float* __restrict__ pred,
        const float* __restrict__ target,
        float* __restrict__ partial) {
    __shared__ float swave[NT / 64];

    const int t    = threadIdx.x;
    const int lane = t & 63;
    const int wv   = t >> 6;
    const int c    = t * 4;                  // column strip (NT*4 == WW)

    // --- XCD-contiguous swizzle: l -> (img, h0) ---
    const int l    = blockIdx.x;             // [0, 1024)
    const int xcd  = l & 7;
    const int j    = l >> 3;                 // [0, 128)
    const int img  = j >> 3;                 // [0, 16)
    const int slab = j & 7;                  // [0, 8)
    const int h0   = xcd * (8 * RPB) + slab * RPB;

    const float* timg = target + (size_t)img * HH * WW;
    const float* pimg = pred   + (size_t)img * HH * WW;
    const float* tp   = timg + (size_t)h0 * WW + c;   // target strip base
    const float* pp   = pimg + (size_t)h0 * WW + c;   // pred strip base

    const bool top = (h0 > 0);
    const bool bot = (h0 + RPB < HH);
    const float4 zero = make_float4(0.0f, 0.0f, 0.0f, 0.0f);

    // halo column (c-1 for lane0, c+4 for lane63) — 2 active lanes/wave
    const bool hval = (lane == 0) ? (c > 0) : ((lane == 63) ? (c + 4 < WW) : false);
    const float* thp = timg + (size_t)h0 * WW + ((lane == 0) ? (c - 1) : (c + 4));

    // Rolling window in NAMED registers (no arrays -> no scratch).
    // tA..tE = target rows r-1 .. r+3 ; xA..xC = pred rows r .. r+2 ;
    // hA..hE = halo column, same rows as tA..tE.
    float4 tA, tB, tC, tD, tE;
    float4 xA, xB, xC;
    float  hA = 0.0f, hB = 0.0f, hC = 0.0f, hD = 0.0f, hE = 0.0f;

    // ---- prologue: target rows -1..2, pred rows 0..1 ----
    tA = top ? *(const float4*)(tp - WW) : zero;
    tB = *(const float4*)(tp);
    tC = *(const float4*)(tp + WW);
    tD = *(const float4*)(tp + 2 * WW);
    xA = *(const float4*)(pp);
    xB = *(const float4*)(pp + WW);
    if (hval) {
        if (top) hA = *(thp - WW);
        hB = thp[0];
        hC = thp[WW];
        hD = thp[2 * WW];
    }

    float s = 0.0f;

    // One step = prefetch row r+3 (target+halo) and row r+2 (pred),
    // compute row r from the window, rotate. All indices compile-time.
    #define STEP(r)                                                              \
    {                                                                            \
        if ((r) + 3 < RPB) {                                                     \
            tE = *(const float4*)(tp + (size_t)((r) + 3) * WW);                  \
            hE = hval ? thp[(size_t)((r) + 3) * WW] : 0.0f;                      \
        } else if ((r) + 3 == RPB) {                                             \
            tE = bot ? *(const float4*)(tp + (size_t)RPB * WW) : zero;           \
            hE = (hval && bot) ? thp[(size_t)RPB * WW] : 0.0f;                   \
        } else {                                                                 \
            tE = zero; hE = 0.0f;                                                \
        }                                                                        \
        if ((r) + 2 < RPB) xC = *(const float4*)(pp + (size_t)((r) + 2) * WW);   \
        else               xC = zero;                                            \
                                                                                 \
        float4 vm = make_float4(fmax3(tA.x, tB.x, tC.x), fmax3(tA.y, tB.y, tC.y),\
                                fmax3(tA.z, tB.z, tC.z), fmax3(tA.w, tB.w, tC.w));\
        float hmax = fmax3(hA, hB, hC);                                          \
        float lft = __shfl_up(vm.w, 1);                                          \
        float rgt = __shfl_down(vm.x, 1);                                        \
        if (lane == 0)  lft = hmax;                                              \
        if (lane == 63) rgt = hmax;                                              \
        float d0 = fmax3(lft,  vm.x, vm.y);                                      \
        float d1 = fmax3(vm.x, vm.y, vm.z);                                      \
        float d2 = fmax3(vm.y, vm.z, vm.w);                                      \
        float d3 = fmax3(vm.z, vm.w, rgt);                                       \
        s += loss_elem(xA.x, tB.x, d0);                                          \
        s += loss_elem(xA.y, tB.y, d1);                                          \
        s += loss_elem(xA.z, tB.z, d2);                                          \
        s += loss_elem(xA.w, tB.w, d3);                                          \
        tA = tB; tB = tC; tC = tD; tD = tE;                                      \
        hA = hB; hB = hC; hC = hD; hD = hE;                                      \
        xA = xB; xB = xC;                                                        \
    }

    STEP(0)  STEP(1)  STEP(2)  STEP(3)
    STEP(4)  STEP(5)  STEP(6)  STEP(7)
    STEP(8)  STEP(9)  STEP(10) STEP(11)
    STEP(12) STEP(13) STEP(14) STEP(15)
    #undef STEP

    // ---- wave reduction ----
    #pragma unroll
    for (int off = 32; off > 0; off >>= 1)
        s += __shfl_down(s, off);

    if (PER_WAVE) {
        if (lane == 0)
            partial[(size_t)l * (NT / 64) + wv] = s;   // no barrier, no LDS
    } else {
        if (lane == 0) swave[wv] = s;
        __syncthreads();
        if (t == 0) {
            float tot = 0.0f;
            #pragma unroll
            for (int i = 0; i < NT / 64; ++i) tot += swave[i];
            partial[l] = tot;
        }
    }
}

__global__ __launch_bounds__(1024) void dilatedweightBCE_reduce(
        const float* __restrict__ partial,
        float* __restrict__ out,
        int npart4,            // number of float4 chunks
        float inv_n) {
    __shared__ float swave[16];
    const int t = threadIdx.x;

    float s = 0.0f;
    const float4* p4 = (const float4*)partial;
    for (int i = t; i < npart4; i += 1024) {
        float4 v = p4[i];
        s += v.x + v.y + v.z + v.w;
    }

    #pragma unroll
    for (int off = 32; off > 0; off >>= 1)
        s += __shfl_down(s, off);

    const int lane = t & 63;
    if (lane == 0) swave[t >> 6] = s;
    __syncthreads();
    if (t == 0) {
        float tot = 0.0f;
        #pragma unroll
        for (int i = 0; i < 16; ++i) tot += swave[i];
        out[0] = tot * inv_n;
    }
}

extern "C" void kernel_launch(void* const* d_in, const int* in_sizes, int n_in,
                              void* d_out, int out_size, void* d_ws, size_t ws_size,
                              hipStream_t stream) {
    const float* pred   = (const float*)d_in[0];
    const float* target = (const float*)d_in[1];
    float* out     = (float*)d_out;
    float* partial = (float*)d_ws;

    const int n  = in_sizes[0];              // B*C*H*W
    const int Bn = n / (HH * WW);            // batch (16)
    const int nblocks = (HH / RPB) * Bn;     // 1024

    const size_t need = (size_t)nblocks * (NT / 64) * sizeof(float);  // 16 KB
    if (ws_size >= need) {
        dilatedweightBCE_main<true><<<nblocks, NT, 0, stream>>>(pred, target, partial);
        dilatedweightBCE_reduce<<<1, 1024, 0, stream>>>(partial, out,
                                                        nblocks * (NT / 64) / 4,
                                                        1.0f / (float)n);
    } else {
        dilatedweightBCE_main<false><<<nblocks, NT, 0, stream>>>(pred, target, partial);
        dilatedweightBCE_reduce<<<1, 1024, 0, stream>>>(partial, out,
                                                        nblocks / 4,
                                                        1.0f / (float)n);
    }
}

// Round 3
// 146.781 us; speedup vs baseline: 1.2831x; 1.2630x over previous
//
#include <hip/hip_runtime.h>

// Problem constants (from reference): B=16, C=1, H=1024, W=1024, fp32.
#define HH 1024
#define WW 1024
#define BAND 8           // rows per block; thread = 8 rows x float4 strip
#define NT 256

// ext_vector type so __builtin_nontemporal_load accepts it (HIP float4 is a
// struct; the builtin needs scalar/vector).
typedef __attribute__((ext_vector_type(4))) float f32x4;

__device__ __forceinline__ float fmax3(float a, float b, float c) {
    return fmaxf(a, fmaxf(b, c));
}

__device__ __forceinline__ float loss_elem(float x, float t, float dil) {
    // target/dilated are exactly binary {0,1}: weight = 1 + 4*dil + 15*t
    float w = fmaf(15.0f, t, fmaf(4.0f, dil, 1.0f));
    // BCE with logits: max(x,0) - x*t + log1p(exp(-|x|))
    float a  = fabsf(x);
    float sp = __logf(1.0f + __expf(-a));
    return w * (fmaxf(x, 0.0f) - x * t + sp);
}

// R12: exact R9 structure (42.9us verified; rolling-window R10/R11 regressed
// 2.2x — burst-and-die is the winning issue shape) + ONE perturbation:
// NONTEMPORAL bulk loads. nt prevents L2/L3 allocation, so every iteration
// streams all 147MB from HBM. This is a designed experiment on what caps R9
// at 3.43 TB/s delivered reads:
//   (a) L3-read-BW-bound (~2 TB/s): all-HBM streams faster -> ~31us
//   (b) platform read ceiling ~3.4 TB/s: unchanged -> ~45us
//   (c) per-CU MSHR x latency bound: higher avg latency -> ~55us
// FETCH_SIZE must jump 66MB -> ~140MB to confirm nt took effect.
// Halo column loads stay cached (2 lanes/wave, 64B lines, cheap).
template <bool PER_WAVE>
__global__ __launch_bounds__(NT, 4) void dilatedweightBCE_main(
        const float* __restrict__ pred,
        const float* __restrict__ target,
        float* __restrict__ partial) {
    __shared__ float swave[NT / 64];

    const int t    = threadIdx.x;
    const int lane = t & 63;
    const int wv   = t >> 6;
    const int c    = t * 4;                  // column strip (NT*4 == WW)

    // --- XCD-contiguous swizzle: l -> (img, h0) ---
    const int l    = blockIdx.x;             // [0, 2048)
    const int xcd  = l & 7;
    const int j    = l >> 3;                 // [0, 256)
    const int img  = j >> 4;                 // [0, 16)
    const int band = j & 15;                 // [0, 16)
    const int h0   = (xcd * 16 + band) * BAND;   // XCD x owns rows [128x,128x+128)

    const float* timg = target + (size_t)img * HH * WW;
    const float* pimg = pred   + (size_t)img * HH * WW;
    const f32x4 zero = (f32x4)(0.0f);

    // ---- ALL 18 independent loads issued before any use (nontemporal) ----
    f32x4 tr[BAND + 2];                     // target rows h0-1 .. h0+BAND
    tr[0] = (h0 > 0)
          ? __builtin_nontemporal_load((const f32x4*)(timg + (size_t)(h0 - 1) * WW + c))
          : zero;
    #pragma unroll
    for (int r = 0; r < BAND; ++r)
        tr[r + 1] = __builtin_nontemporal_load(
            (const f32x4*)(timg + (size_t)(h0 + r) * WW + c));
    tr[BAND + 1] = (h0 + BAND < HH)
          ? __builtin_nontemporal_load((const f32x4*)(timg + (size_t)(h0 + BAND) * WW + c))
          : zero;

    f32x4 xr[BAND];                         // pred rows h0 .. h0+BAND-1
    #pragma unroll
    for (int r = 0; r < BAND; ++r)
        xr[r] = __builtin_nontemporal_load(
            (const f32x4*)(pimg + (size_t)(h0 + r) * WW + c));

    // ---- halo column for wave-boundary lanes (normal cached loads) ----
    float halo[BAND];
    #pragma unroll
    for (int r = 0; r < BAND; ++r) halo[r] = 0.0f;
    if (lane == 0 || lane == 63) {
        const int pc = (lane == 0) ? c - 1 : c + 4;
        if (pc >= 0 && pc < WW) {
            float hv[BAND + 2];
            hv[0] = (h0 > 0) ? timg[(size_t)(h0 - 1) * WW + pc] : 0.0f;
            #pragma unroll
            for (int r = 0; r < BAND; ++r)
                hv[r + 1] = timg[(size_t)(h0 + r) * WW + pc];
            hv[BAND + 1] = (h0 + BAND < HH)
                         ? timg[(size_t)(h0 + BAND) * WW + pc] : 0.0f;
            #pragma unroll
            for (int r = 0; r < BAND; ++r)
                halo[r] = fmax3(hv[r], hv[r + 1], hv[r + 2]);
        }
    }

    // ---- dilation + loss, row by row (row j needs only tr[j..j+2]) ----
    float s = 0.0f;
    #pragma unroll
    for (int r = 0; r < BAND; ++r) {
        f32x4 a = tr[r], m = tr[r + 1], d = tr[r + 2];
        float vmx = fmax3(a.x, m.x, d.x);
        float vmy = fmax3(a.y, m.y, d.y);
        float vmz = fmax3(a.z, m.z, d.z);
        float vmw = fmax3(a.w, m.w, d.w);

        float lft = __shfl_up(vmw, 1);
        float rgt = __shfl_down(vmx, 1);
        if (lane == 0)  lft = halo[r];
        if (lane == 63) rgt = halo[r];

        float d0 = fmax3(lft, vmx, vmy);
        float d1 = fmax3(vmx, vmy, vmz);
        float d2 = fmax3(vmy, vmz, vmw);
        float d3 = fmax3(vmz, vmw, rgt);

        f32x4 x = xr[r];
        s += loss_elem(x.x, m.x, d0);
        s += loss_elem(x.y, m.y, d1);
        s += loss_elem(x.z, m.z, d2);
        s += loss_elem(x.w, m.w, d3);
    }

    // ---- wave reduction ----
    #pragma unroll
    for (int off = 32; off > 0; off >>= 1)
        s += __shfl_down(s, off);

    if (PER_WAVE) {
        if (lane == 0)
            partial[(size_t)l * (NT / 64) + wv] = s;   // no barrier, no LDS
    } else {
        if (lane == 0) swave[wv] = s;
        __syncthreads();
        if (t == 0) {
            float tot = 0.0f;
            #pragma unroll
            for (int i = 0; i < NT / 64; ++i) tot += swave[i];
            partial[l] = tot;
        }
    }
}

__global__ __launch_bounds__(1024) void dilatedweightBCE_reduce(
        const float* __restrict__ partial,
        float* __restrict__ out,
        int npart4,            // number of float4 chunks
        float inv_n) {
    __shared__ float swave[16];
    const int t = threadIdx.x;

    float s = 0.0f;
    const float4* p4 = (const float4*)partial;
    for (int i = t; i < npart4; i += 1024) {
        float4 v = p4[i];
        s += v.x + v.y + v.z + v.w;
    }

    #pragma unroll
    for (int off = 32; off > 0; off >>= 1)
        s += __shfl_down(s, off);

    const int lane = t & 63;
    if (lane == 0) swave[t >> 6] = s;
    __syncthreads();
    if (t == 0) {
        float tot = 0.0f;
        #pragma unroll
        for (int i = 0; i < 16; ++i) tot += swave[i];
        out[0] = tot * inv_n;
    }
}

extern "C" void kernel_launch(void* const* d_in, const int* in_sizes, int n_in,
                              void* d_out, int out_size, void* d_ws, size_t ws_size,
                              hipStream_t stream) {
    const float* pred   = (const float*)d_in[0];
    const float* target = (const float*)d_in[1];
    float* out     = (float*)d_out;
    float* partial = (float*)d_ws;

    const int n  = in_sizes[0];              // B*C*H*W
    const int Bn = n / (HH * WW);            // batch (16)
    const int nblocks = (HH / BAND) * Bn;    // 2048

    const size_t need = (size_t)nblocks * (NT / 64) * sizeof(float);  // 32 KB
    if (ws_size >= need) {
        dilatedweightBCE_main<true><<<nblocks, NT, 0, stream>>>(pred, target, partial);
        dilatedweightBCE_reduce<<<1, 1024, 0, stream>>>(partial, out,
                                                        nblocks * (NT / 64) / 4,
                                                        1.0f / (float)n);
    } else {
        dilatedweightBCE_main<false><<<nblocks, NT, 0, stream>>>(pred, target, partial);
        dilatedweightBCE_reduce<<<1, 1024, 0, stream>>>(partial, out,
                                                        nblocks / 4,
                                                        1.0f / (float)n);
    }
}